// Round 4
// baseline (278.705 us; speedup 1.0000x reference)
//
#include <hip/hip_runtime.h>

#define SLEN 2048
#define NB 2
#define NHQ 32
#define NHK 8
#define DH 128
#define QBLK 256
#define KVBLK 64
#define NT (SLEN / KVBLK)
#define TILE_B (KVBLK * DH * 2)   // 16384 bytes per staged tile image

typedef float  f32x4  __attribute__((ext_vector_type(4)));
typedef short  bf16x8 __attribute__((ext_vector_type(8)));

__device__ __forceinline__ unsigned short f2bf(float f) {
  union { float f; unsigned int u; } v; v.f = f;
  return (unsigned short)((v.u + 0x7fffu + ((v.u >> 16) & 1u)) >> 16);
}

__device__ __forceinline__ unsigned int cvtpk(float a, float b) {
  unsigned int r;
  asm("v_cvt_pk_bf16_f32 %0, %1, %2" : "=v"(r) : "v"(a), "v"(b));
  return r;
}

// async global->LDS, 16B per lane. LDS dest is wave-uniform; HW adds lane*16.
#define GLOAD16(g, l)                                                                   \
  __builtin_amdgcn_global_load_lds(                                                    \
      (const __attribute__((address_space(1))) unsigned int*)(g),                      \
      (__attribute__((address_space(3))) unsigned int*)(l), 16, 0, 0)

// ---------------- prep: fp32 K/V -> bf16 pre-swizzled LDS tile images in ws ---------
__global__ __launch_bounds__(256)
void prep_kv(const float* __restrict__ K, const float* __restrict__ V,
             unsigned short* __restrict__ W) {
  const int tile = blockIdx.x;
  const int bh   = blockIdx.y;          // b*NHK + kh
  const int tid  = threadIdx.x;
  const size_t krs = (size_t)NB * NHK * DH;
  const float* kb = K + (size_t)bh * DH + (size_t)tile * KVBLK * krs;
  const float* vb = V + (size_t)bh * DH + (size_t)tile * KVBLK * krs;
  unsigned short* kd = W + ((size_t)bh * NT + tile) * (KVBLK * DH);
  unsigned short* vd = W + (size_t)NB * NHK * NT * (KVBLK * DH)
                         + ((size_t)bh * NT + tile) * (KVBLK * DH);
#pragma unroll
  for (int i = 0; i < 4; ++i) {
    const int cid  = tid + 256 * i;
    const int row  = cid >> 4;                 // kv row
    const int cpos = (cid & 15) << 4;          // dst byte pos
    const int cb   = cpos ^ ((row & 7) << 4);  // src byte col
    const float* s = kb + (size_t)row * krs + (cb >> 1);
    float4 f0 = *(const float4*)s;
    float4 f1 = *(const float4*)(s + 4);
    bf16x8 a;
    a[0]=(short)f2bf(f0.x); a[1]=(short)f2bf(f0.y); a[2]=(short)f2bf(f0.z); a[3]=(short)f2bf(f0.w);
    a[4]=(short)f2bf(f1.x); a[5]=(short)f2bf(f1.y); a[6]=(short)f2bf(f1.z); a[7]=(short)f2bf(f1.w);
    *(bf16x8*)((char*)kd + row * 256 + cpos) = a;
  }
#pragma unroll
  for (int i = 0; i < 4; ++i) {
    const int cid  = tid + 256 * i;
    const int d    = cid >> 3;
    const int cpos = (cid & 7) << 4;
    const int kb2  = cpos ^ ((d & 7) << 4);
    const int kv   = kb2 >> 1;
    bf16x8 a;
#pragma unroll
    for (int j = 0; j < 8; ++j) a[j] = (short)f2bf(vb[(size_t)(kv + j) * krs + d]);
    *(bf16x8*)((char*)vd + d * 128 + cpos) = a;
  }
}

// -------- main attention kernel: 8 waves x 32 q-rows (2x16 strips), swapped QK^T ----
__global__ __launch_bounds__(512, 2)
void fattn_fwd(const float* __restrict__ Q, const unsigned short* __restrict__ KW,
               const unsigned short* __restrict__ VW, float* __restrict__ O) {
  const int tid  = threadIdx.x;
  const int w    = tid >> 6;        // wave 0..7
  const int lane = tid & 63;
  const int l15  = lane & 15;
  const int g    = lane >> 4;       // 16-lane group 0..3

  const int qt = (int)gridDim.x - 1 - (int)blockIdx.x;  // big tiles dispatch first
  const int hb = blockIdx.y;
  const int b  = hb >> 5;
  const int h  = hb & (NHQ - 1);
  const int kh = h >> 2;

  const int qb  = qt * QBLK;
  const int qs0 = qb + 32 * w;      // wave's first q row (owns 32 rows, 2 strips)

  __shared__ alignas(16) unsigned short Kbuf[2][KVBLK * DH];   // 2x16KB
  __shared__ alignas(16) unsigned short Vbuf[2][DH * KVBLK];   // 2x16KB

  const char* kws = (const char*)(KW + ((size_t)(b * NHK + kh) * NT) * (KVBLK * DH));
  const char* vws = (const char*)(VW + ((size_t)(b * NHK + kh) * NT) * (KVBLK * DH));

  const float sc = 0.08838834764831845f * 1.4426950408889634f;  // 1/sqrt(128)*log2(e)

  // ---- Q fragments: fp32 -> (scaled) bf16 in reg, once per block ----
  bf16x8 qa[2][4];
#pragma unroll
  for (int u = 0; u < 2; ++u) {
    const float* qp = Q + ((size_t)((qs0 + 16 * u + l15) * NB + b) * NHQ + h) * DH;
#pragma unroll
    for (int s = 0; s < 4; ++s) {
      const float* p = qp + 32 * s + 8 * g;
      float4 f0 = *(const float4*)(p);
      float4 f1 = *(const float4*)(p + 4);
      bf16x8 a;
      a[0]=(short)f2bf(f0.x*sc); a[1]=(short)f2bf(f0.y*sc);
      a[2]=(short)f2bf(f0.z*sc); a[3]=(short)f2bf(f0.w*sc);
      a[4]=(short)f2bf(f1.x*sc); a[5]=(short)f2bf(f1.y*sc);
      a[6]=(short)f2bf(f1.z*sc); a[7]=(short)f2bf(f1.w*sc);
      qa[u][s] = a;
    }
  }

  f32x4 o[2][8];
#pragma unroll
  for (int u = 0; u < 2; ++u)
#pragma unroll
    for (int dt = 0; dt < 8; ++dt) o[u][dt] = (f32x4){0.f, 0.f, 0.f, 0.f};
  float m[2] = {-1e30f, -1e30f}, lsum[2] = {0.f, 0.f};

  const int nt = 4 * qt + 4;

  // ---- prologue: stage tile 0 into buffer 0 ----
#pragma unroll
  for (int i = 0; i < 2; ++i) {
    const int off = i * 8192 + w * 1024;
    GLOAD16(kws + off + (lane << 4), (char*)Kbuf[0] + off);
    GLOAD16(vws + off + (lane << 4), (char*)Vbuf[0] + off);
  }

  int cur = 0;
  for (int it = 0; it < nt; ++it) {
    if (it + 1 < nt) {
      const char* ks = kws + (size_t)(it + 1) * TILE_B;
      const char* vs = vws + (size_t)(it + 1) * TILE_B;
#pragma unroll
      for (int i = 0; i < 2; ++i) {
        const int off = i * 8192 + w * 1024;
        GLOAD16(ks + off + (lane << 4), (char*)Kbuf[cur ^ 1] + off);
        GLOAD16(vs + off + (lane << 4), (char*)Vbuf[cur ^ 1] + off);
      }
      asm volatile("s_waitcnt vmcnt(4)" ::: "memory");  // current tile's 4 loads done
    } else {
      asm volatile("s_waitcnt vmcnt(0)" ::: "memory");
    }
    __builtin_amdgcn_s_barrier();
    asm volatile("" ::: "memory");

    const unsigned short* Kc = Kbuf[cur];
    const unsigned short* Vc = Vbuf[cur];
    const int kv0 = it * KVBLK;

#pragma unroll
    for (int u = 0; u < 2; ++u) {
      const int qs = qs0 + 16 * u;
      if (kv0 > qs + 15) continue;   // strip fully masked
      const int qrow = qs + l15;

      // ---- swapped QK^T: S^T[64 kv][16 q]; lane owns q=qrow, kv=16c+4g+r ----
      f32x4 acc[4];
#pragma unroll
      for (int c = 0; c < 4; ++c) acc[c] = (f32x4){0.f, 0.f, 0.f, 0.f};
      __builtin_amdgcn_s_setprio(1);
#pragma unroll
      for (int s = 0; s < 4; ++s) {
        const int cb = 64 * s + 16 * g;
#pragma unroll
        for (int c = 0; c < 4; ++c) {
          const int row = 16 * c + l15;
          bf16x8 kfr = *(const bf16x8*)((const char*)Kc + row * 256 + (cb ^ ((row & 7) << 4)));
          acc[c] = __builtin_amdgcn_mfma_f32_16x16x32_bf16(kfr, qa[u][s], acc[c], 0, 0, 0);
        }
      }
      __builtin_amdgcn_s_setprio(0);

      // ---- in-register masked online softmax (exp2 domain, defer-max) ----
      const bool domask = (kv0 + KVBLK - 1 > qs);
      float p[4][4];
#pragma unroll
      for (int c = 0; c < 4; ++c)
#pragma unroll
        for (int r = 0; r < 4; ++r) {
          float v = acc[c][r];
          if (domask) {
            const int kv = kv0 + 16 * c + 4 * g + r;
            v = (kv > qrow) ? -1e30f : v;
          }
          p[c][r] = v;
        }
      // max tree (max3-fusable)
      float t0 = fmaxf(fmaxf(p[0][0], p[0][1]), p[0][2]);
      float t1 = fmaxf(fmaxf(p[0][3], p[1][0]), p[1][1]);
      float t2 = fmaxf(fmaxf(p[1][2], p[1][3]), p[2][0]);
      float t3 = fmaxf(fmaxf(p[2][1], p[2][2]), p[2][3]);
      float t4 = fmaxf(fmaxf(p[3][0], p[3][1]), p[3][2]);
      float pm = fmaxf(fmaxf(fmaxf(t0, t1), t2), fmaxf(fmaxf(t3, t4), p[3][3]));
      pm = fmaxf(pm, __shfl_xor(pm, 16));
      pm = fmaxf(pm, __shfl_xor(pm, 32));

      if (!__all((int)(pm <= m[u] + 11.0f))) {
        const float mn = fmaxf(m[u], pm);
        const float fr = exp2f(m[u] - mn);
        m[u] = mn;
        lsum[u] *= fr;
#pragma unroll
        for (int dt = 0; dt < 8; ++dt) o[u][dt] = o[u][dt] * fr;
      }
      float ps = 0.f;
      const float mb = m[u];
#pragma unroll
      for (int c = 0; c < 4; ++c)
#pragma unroll
        for (int r = 0; r < 4; ++r) {
          const float e = exp2f(p[c][r] - mb);
          p[c][r] = e;
          ps += e;
        }
      ps += __shfl_xor(ps, 16);
      ps += __shfl_xor(ps, 32);
      lsum[u] += ps;

      // ---- pack P^T to bf16 pairs (v_cvt_pk_bf16_f32) ----
      unsigned int pk[4][2];
#pragma unroll
      for (int c = 0; c < 4; ++c)
#pragma unroll
        for (int rr = 0; rr < 2; ++rr)
          pk[c][rr] = cvtpk(p[c][2 * rr], p[c][2 * rr + 1]);

      // ---- redistribute to PV B-fragment layout (fixed cross-group shuffle) ----
      int pa32[2][4];
      const bool hi2 = (g >= 2);
#pragma unroll
      for (int ks = 0; ks < 2; ++ks)
#pragma unroll
        for (int j = 0; j < 4; ++j) {
          const int srcl = (((2 * g + (j >> 1)) & 3) << 4) + l15;
          const int va  = __shfl((int)pk[2 * ks][j & 1], srcl);
          const int vb2 = __shfl((int)pk[2 * ks + 1][j & 1], srcl);
          pa32[ks][j] = hi2 ? vb2 : va;
        }

      // ---- PV: O[16 q][128 d] += (V^T frag) x (P^T frag) ----
      __builtin_amdgcn_s_setprio(1);
#pragma unroll
      for (int ks = 0; ks < 2; ++ks) {
        union { int u32[4]; bf16x8 v; } pu;
        pu.u32[0] = pa32[ks][0]; pu.u32[1] = pa32[ks][1];
        pu.u32[2] = pa32[ks][2]; pu.u32[3] = pa32[ks][3];
        const bf16x8 pa = pu.v;
#pragma unroll
        for (int dt = 0; dt < 8; ++dt) {
          const int d = 16 * dt + l15;
          bf16x8 vfr = *(const bf16x8*)((const char*)Vc + d * 128 +
                                        ((64 * ks + 16 * g) ^ ((d & 7) << 4)));
          o[u][dt] = __builtin_amdgcn_mfma_f32_16x16x32_bf16(vfr, pa, o[u][dt], 0, 0, 0);
        }
      }
      __builtin_amdgcn_s_setprio(0);
    }

    asm volatile("" ::: "memory");
    __builtin_amdgcn_s_barrier();   // all reads of buf[cur] done before overwrite
    cur ^= 1;
  }

  // ---- epilogue: normalize, store fp32 [s, b, h*d]; lane holds O[qrow][16dt+4g+r] ----
#pragma unroll
  for (int u = 0; u < 2; ++u) {
    const float rl = 1.0f / lsum[u];
    const int qrow = qs0 + 16 * u + l15;
    float* ob = O + ((size_t)b * NHQ + h) * DH + (size_t)qrow * (NB * NHQ * DH);
#pragma unroll
    for (int dt = 0; dt < 8; ++dt) {
      float4 st;
      st.x = o[u][dt][0] * rl; st.y = o[u][dt][1] * rl;
      st.z = o[u][dt][2] * rl; st.w = o[u][dt][3] * rl;
      *(float4*)(ob + 16 * dt + 4 * g) = st;
    }
  }
}

extern "C" void kernel_launch(void* const* d_in, const int* in_sizes, int n_in,
                              void* d_out, int out_size, void* d_ws, size_t ws_size,
                              hipStream_t stream) {
  const float* Q = (const float*)d_in[0];
  const float* K = (const float*)d_in[1];
  const float* V = (const float*)d_in[2];
  float* Out = (float*)d_out;
  unsigned short* W = (unsigned short*)d_ws;   // needs 16.78 MB

  dim3 pgrid(NT, NB * NHK);
  prep_kv<<<pgrid, 256, 0, stream>>>(K, V, W);

  const unsigned short* KW = W;
  const unsigned short* VW = W + (size_t)NB * NHK * NT * (KVBLK * DH);
  dim3 grid(SLEN / QBLK, NB * NHQ);
  fattn_fwd<<<grid, 512, 0, stream>>>(Q, KW, VW, Out);
}

// Round 5
// 149.089 us; speedup vs baseline: 1.8694x; 1.8694x over previous
//
#include <hip/hip_runtime.h>

#define SLEN 2048
#define NB 2
#define NHQ 32
#define NHK 8
#define DH 128
#define QBLK 128
#define KVBLK 64
#define NT (SLEN / KVBLK)
#define NQT (SLEN / QBLK)
#define TILE_B (KVBLK * DH * 2)   // 16384 bytes per staged tile image

typedef float  f32x4  __attribute__((ext_vector_type(4)));
typedef short  bf16x8 __attribute__((ext_vector_type(8)));

__device__ __forceinline__ unsigned short f2bf(float f) {
  union { float f; unsigned int u; } v; v.f = f;
  return (unsigned short)((v.u + 0x7fffu + ((v.u >> 16) & 1u)) >> 16);
}

__device__ __forceinline__ unsigned int cvtpk(float a, float b) {
  unsigned int r;
  asm("v_cvt_pk_bf16_f32 %0, %1, %2" : "=v"(r) : "v"(a), "v"(b));
  return r;
}

// async global->LDS, 16B per lane. LDS dest is wave-uniform; HW adds lane*16.
#define GLOAD16(g, l)                                                                   \
  __builtin_amdgcn_global_load_lds(                                                    \
      (const __attribute__((address_space(1))) unsigned int*)(g),                      \
      (__attribute__((address_space(3))) unsigned int*)(l), 16, 0, 0)

// ---------------- prep: fp32 K/V -> bf16 pre-swizzled LDS tile images in ws ---------
// K image: [kv=64 rows of 256B], byte p in row holds K[kv][(p^((kv&7)<<4))/2..]
// V image: [d=128 rows of 128B], linear slot p (after XOR unswizzle) holds
//          V[kvperm(p)][d], kvperm(p) = bits {p5, p2, p4, p3, p1, p0} -- chosen so
//          the QK^T output registers ARE the PV B-fragment (zero cross-lane moves).
__global__ __launch_bounds__(256)
void prep_kv(const float* __restrict__ K, const float* __restrict__ V,
             unsigned short* __restrict__ W) {
  const int tile = blockIdx.x;
  const int bh   = blockIdx.y;          // b*NHK + kh
  const int tid  = threadIdx.x;
  const size_t krs = (size_t)NB * NHK * DH;
  const float* kb = K + (size_t)bh * DH + (size_t)tile * KVBLK * krs;
  const float* vb = V + (size_t)bh * DH + (size_t)tile * KVBLK * krs;
  unsigned short* kd = W + ((size_t)bh * NT + tile) * (KVBLK * DH);
  unsigned short* vd = W + (size_t)NB * NHK * NT * (KVBLK * DH)
                         + ((size_t)bh * NT + tile) * (KVBLK * DH);
#pragma unroll
  for (int i = 0; i < 4; ++i) {
    const int cid  = tid + 256 * i;
    const int row  = cid >> 4;                 // kv row
    const int cpos = (cid & 15) << 4;          // dst byte pos
    const int cb   = cpos ^ ((row & 7) << 4);  // src byte col
    const float* s = kb + (size_t)row * krs + (cb >> 1);
    float4 f0 = *(const float4*)s;
    float4 f1 = *(const float4*)(s + 4);
    bf16x8 a;
    a[0]=(short)f2bf(f0.x); a[1]=(short)f2bf(f0.y); a[2]=(short)f2bf(f0.z); a[3]=(short)f2bf(f0.w);
    a[4]=(short)f2bf(f1.x); a[5]=(short)f2bf(f1.y); a[6]=(short)f2bf(f1.z); a[7]=(short)f2bf(f1.w);
    *(bf16x8*)((char*)kd + row * 256 + cpos) = a;
  }
#pragma unroll
  for (int i = 0; i < 4; ++i) {
    const int cid  = tid + 256 * i;
    const int d    = cid >> 3;
    const int cpos = (cid & 7) << 4;
    const int kb2  = cpos ^ ((d & 7) << 4);
    const int p0   = kb2 >> 1;                 // linear slot base (multiple of 8)
    bf16x8 a;
#pragma unroll
    for (int j = 0; j < 8; ++j) {
      const int p  = p0 + j;
      const int kv = (p & 32) | ((p & 4) << 2) | ((p & 24) >> 1) | (p & 3);
      a[j] = (short)f2bf(vb[(size_t)kv * krs + d]);
    }
    *(bf16x8*)((char*)vd + d * 128 + cpos) = a;
  }
}

// -------- main: 4 waves x 32 q-rows (2 strips, shared operands), paired q-tiles -----
__global__ __launch_bounds__(256, 2)
void fattn_fwd(const float* __restrict__ Q, const unsigned short* __restrict__ KW,
               const unsigned short* __restrict__ VW, float* __restrict__ O) {
  const int tid  = threadIdx.x;
  const int w    = tid >> 6;        // wave 0..3
  const int lane = tid & 63;
  const int l15  = lane & 15;
  const int g    = lane >> 4;       // 16-lane group 0..3

  const int pr = blockIdx.x;        // pair index 0..7
  const int hb = blockIdx.y;
  const int b  = hb >> 5;
  const int h  = hb & (NHQ - 1);
  const int kh = h >> 2;

  __shared__ alignas(16) unsigned short Kbuf[2][KVBLK * DH];   // 2x16KB
  __shared__ alignas(16) unsigned short Vbuf[2][DH * KVBLK];   // 2x16KB

  const char* kws = (const char*)(KW + ((size_t)(b * NHK + kh) * NT) * (KVBLK * DH));
  const char* vws = (const char*)(VW + ((size_t)(b * NHK + kh) * NT) * (KVBLK * DH));

  const float sc = 0.08838834764831845f * 1.4426950408889634f;  // 1/sqrt(128)*log2(e)

  // two q-tiles per block: big one first -> total work uniform across all blocks
  for (int ph = 0; ph < 2; ++ph) {
    const int qt  = ph ? pr : (NQT - 1 - pr);
    const int qs0 = qt * QBLK + 32 * w;   // wave's first q row (2 strips of 16)
    const int nt  = 2 * qt + 2;

    // ---- Q fragments: fp32 -> (scaled) bf16 in reg ----
    bf16x8 qa[2][4];
#pragma unroll
    for (int u = 0; u < 2; ++u) {
      const float* qp = Q + ((size_t)((qs0 + 16 * u + l15) * NB + b) * NHQ + h) * DH;
#pragma unroll
      for (int s = 0; s < 4; ++s) {
        const float* p = qp + 32 * s + 8 * g;
        float4 f0 = *(const float4*)(p);
        float4 f1 = *(const float4*)(p + 4);
        bf16x8 a;
        a[0]=(short)f2bf(f0.x*sc); a[1]=(short)f2bf(f0.y*sc);
        a[2]=(short)f2bf(f0.z*sc); a[3]=(short)f2bf(f0.w*sc);
        a[4]=(short)f2bf(f1.x*sc); a[5]=(short)f2bf(f1.y*sc);
        a[6]=(short)f2bf(f1.z*sc); a[7]=(short)f2bf(f1.w*sc);
        qa[u][s] = a;
      }
    }

    f32x4 o[2][8];
#pragma unroll
    for (int u = 0; u < 2; ++u)
#pragma unroll
      for (int dt = 0; dt < 8; ++dt) o[u][dt] = (f32x4){0.f, 0.f, 0.f, 0.f};
    float m[2] = {-1e30f, -1e30f}, lsum[2] = {0.f, 0.f};

    // ---- prologue: stage tile 0 into buffer 0 (8 loads/thread, 4 waves, 32KB) ----
#pragma unroll
    for (int i = 0; i < 4; ++i) {
      const int off = i * 4096 + w * 1024;
      GLOAD16(kws + off + (lane << 4), (char*)Kbuf[0] + off);
      GLOAD16(vws + off + (lane << 4), (char*)Vbuf[0] + off);
    }

    int cur = 0;
    for (int it = 0; it < nt; ++it) {
      if (it + 1 < nt) {
        const char* ks = kws + (size_t)(it + 1) * TILE_B;
        const char* vs = vws + (size_t)(it + 1) * TILE_B;
#pragma unroll
        for (int i = 0; i < 4; ++i) {
          const int off = i * 4096 + w * 1024;
          GLOAD16(ks + off + (lane << 4), (char*)Kbuf[cur ^ 1] + off);
          GLOAD16(vs + off + (lane << 4), (char*)Vbuf[cur ^ 1] + off);
        }
        asm volatile("s_waitcnt vmcnt(8)" ::: "memory");  // current tile's 8 done
      } else {
        asm volatile("s_waitcnt vmcnt(0)" ::: "memory");
      }
      __builtin_amdgcn_s_barrier();
      asm volatile("" ::: "memory");

      const unsigned short* Kc = Kbuf[cur];
      const unsigned short* Vc = Vbuf[cur];
      const int kv0 = it * KVBLK;

      if (kv0 <= qs0 + 31) {   // wave has live rows in this tile
        // ---- swapped QK^T, both strips share each K fragment ----
        f32x4 acc[2][4];
#pragma unroll
        for (int u = 0; u < 2; ++u)
#pragma unroll
          for (int c = 0; c < 4; ++c) acc[u][c] = (f32x4){0.f, 0.f, 0.f, 0.f};
        __builtin_amdgcn_s_setprio(1);
#pragma unroll
        for (int s = 0; s < 4; ++s) {
          const int cb = 64 * s + 16 * g;
#pragma unroll
          for (int c = 0; c < 4; ++c) {
            const int row = 16 * c + l15;
            bf16x8 kfr = *(const bf16x8*)((const char*)Kc + row * 256 + (cb ^ ((row & 7) << 4)));
            acc[0][c] = __builtin_amdgcn_mfma_f32_16x16x32_bf16(kfr, qa[0][s], acc[0][c], 0, 0, 0);
            acc[1][c] = __builtin_amdgcn_mfma_f32_16x16x32_bf16(kfr, qa[1][s], acc[1][c], 0, 0, 0);
          }
        }
        __builtin_amdgcn_s_setprio(0);

        // ---- per-strip in-register softmax + P pack (no cross-lane moves) ----
        bf16x8 pav[2][2];
#pragma unroll
        for (int u = 0; u < 2; ++u) {
          const int qs   = qs0 + 16 * u;
          const int qrow = qs + l15;
          const bool domask = (kv0 + KVBLK - 1 > qs);
          float p[4][4];
#pragma unroll
          for (int c = 0; c < 4; ++c)
#pragma unroll
            for (int r = 0; r < 4; ++r) {
              float v = acc[u][c][r];
              if (domask) {
                const int kv = kv0 + 16 * c + 4 * g + r;
                v = (kv > qrow) ? -1e30f : v;
              }
              p[c][r] = v;
            }
          float t0 = fmaxf(fmaxf(p[0][0], p[0][1]), p[0][2]);
          float t1 = fmaxf(fmaxf(p[0][3], p[1][0]), p[1][1]);
          float t2 = fmaxf(fmaxf(p[1][2], p[1][3]), p[2][0]);
          float t3 = fmaxf(fmaxf(p[2][1], p[2][2]), p[2][3]);
          float t4 = fmaxf(fmaxf(p[3][0], p[3][1]), p[3][2]);
          float pm = fmaxf(fmaxf(fmaxf(t0, t1), t2), fmaxf(fmaxf(t3, t4), p[3][3]));
          pm = fmaxf(pm, __shfl_xor(pm, 16));
          pm = fmaxf(pm, __shfl_xor(pm, 32));

          if (!__all((int)(pm <= m[u] + 11.0f))) {
            const float mn = fmaxf(m[u], pm);
            const float fr = exp2f(m[u] - mn);
            m[u] = mn;
            lsum[u] *= fr;
#pragma unroll
            for (int dt = 0; dt < 8; ++dt) o[u][dt] = o[u][dt] * fr;
          }
          float ps = 0.f;
          const float mb = m[u];
#pragma unroll
          for (int c = 0; c < 4; ++c)
#pragma unroll
            for (int r = 0; r < 4; ++r) {
              const float e = exp2f(p[c][r] - mb);
              p[c][r] = e;
              ps += e;
            }
          ps += __shfl_xor(ps, 16);
          ps += __shfl_xor(ps, 32);
          lsum[u] += ps;

          // B-fragment = own registers (V image is kv-permuted to match)
#pragma unroll
          for (int ks = 0; ks < 2; ++ks) {
            union { unsigned int u32[4]; bf16x8 v; } pu;
            pu.u32[0] = cvtpk(p[2 * ks][0], p[2 * ks][1]);
            pu.u32[1] = cvtpk(p[2 * ks][2], p[2 * ks][3]);
            pu.u32[2] = cvtpk(p[2 * ks + 1][0], p[2 * ks + 1][1]);
            pu.u32[3] = cvtpk(p[2 * ks + 1][2], p[2 * ks + 1][3]);
            pav[u][ks] = pu.v;
          }
        }

        // ---- PV: both strips share each V fragment ----
        __builtin_amdgcn_s_setprio(1);
#pragma unroll
        for (int ks = 0; ks < 2; ++ks) {
#pragma unroll
          for (int dt = 0; dt < 8; ++dt) {
            const int d = 16 * dt + l15;
            bf16x8 vfr = *(const bf16x8*)((const char*)Vc + d * 128 +
                                          ((64 * ks + 16 * g) ^ ((d & 7) << 4)));
            o[0][dt] = __builtin_amdgcn_mfma_f32_16x16x32_bf16(vfr, pav[0][ks], o[0][dt], 0, 0, 0);
            o[1][dt] = __builtin_amdgcn_mfma_f32_16x16x32_bf16(vfr, pav[1][ks], o[1][dt], 0, 0, 0);
          }
        }
        __builtin_amdgcn_s_setprio(0);
      }

      asm volatile("" ::: "memory");
      __builtin_amdgcn_s_barrier();   // all reads of buf[cur] done before overwrite
      cur ^= 1;
    }

    // ---- epilogue: normalize, store fp32 [s, b, h*d] ----
#pragma unroll
    for (int u = 0; u < 2; ++u) {
      const float rl = 1.0f / lsum[u];
      const int qrow = qs0 + 16 * u + l15;
      float* ob = O + ((size_t)b * NHQ + h) * DH + (size_t)qrow * (NB * NHQ * DH);
#pragma unroll
      for (int dt = 0; dt < 8; ++dt) {
        float4 st;
        st.x = o[u][dt][0] * rl; st.y = o[u][dt][1] * rl;
        st.z = o[u][dt][2] * rl; st.w = o[u][dt][3] * rl;
        *(float4*)(ob + 16 * dt + 4 * g) = st;
      }
    }
  }
}

extern "C" void kernel_launch(void* const* d_in, const int* in_sizes, int n_in,
                              void* d_out, int out_size, void* d_ws, size_t ws_size,
                              hipStream_t stream) {
  const float* Q = (const float*)d_in[0];
  const float* K = (const float*)d_in[1];
  const float* V = (const float*)d_in[2];
  float* Out = (float*)d_out;
  unsigned short* W = (unsigned short*)d_ws;   // needs 16.78 MB

  dim3 pgrid(NT, NB * NHK);
  prep_kv<<<pgrid, 256, 0, stream>>>(K, V, W);

  const unsigned short* KW = W;
  const unsigned short* VW = W + (size_t)NB * NHK * NT * (KVBLK * DH);
  dim3 grid(NQT / 2, NB * NHQ);
  fattn_fwd<<<grid, 256, 0, stream>>>(Q, KW, VW, Out);
}